// Round 4
// baseline (103.894 us; speedup 1.0000x reference)
//
#include <hip/hip_runtime.h>

// RAVENlog: out = shift*ln2 - Horner4_quantized(0.75 - x*2^-shift)
// shift = floor(log2(x)) + 1 (exact via exponent bits; x in [0.25, 8) is normal)
//
// Quantize(v, iw=7, fw): round-half-even(v*2^fw)/2^fw clamped to [-128, 128-2^-fw].
// All scale muls are powers of two (exact); rintf == jnp.round (half-to-even).
// __f*_rn intrinsics prevent FMA contraction so arithmetic matches the
// reference's separate mul/add rounding bit-exactly.
//
// R4: 4 independent coalesced streams per thread (4 nontemporal loads in
// flight) to keep VMEM busy while the ~30-op VALU chain runs. 99us -> target
// ~90us (copy ceiling 6.29 TB/s = 85us).

typedef float v4f __attribute__((ext_vector_type(4)));

__device__ __forceinline__ float qstep(float acc, float var, float c,
                                       float s, float invs, float hi) {
    float t = __fadd_rn(__fmul_rn(acc, var), c);   // no FMA: match jnp rounding
    float q = __fmul_rn(rintf(__fmul_rn(t, s)), invs);  // exact scale, rne round
    return fminf(fmaxf(q, -128.0f), hi);
}

__device__ __forceinline__ float raven_elem(float x) {
    unsigned int b = __float_as_uint(x);
    float shiftf = (float)((int)((b >> 23) & 0xFFu) - 126);
    float m = __uint_as_float((b & 0x007FFFFFu) | 0x3F000000u);
    float var = __fsub_rn(0.75f, m);   // exact

    const float c0 = 0.2876820724517809f;
    const float c1 = 1.3333333333333333f;
    const float c2 = 0.8888888888888888f;
    const float c3 = 0.7901234567901234f;

    float acc = qstep(0.0f, var, c3,  32.0f, 0.03125f,    128.0f - 0.03125f);
    acc       = qstep(acc,  var, c2,  64.0f, 0.015625f,   128.0f - 0.015625f);
    acc       = qstep(acc,  var, c1, 128.0f, 0.0078125f,  128.0f - 0.0078125f);
    acc       = qstep(acc,  var, c0, 256.0f, 0.00390625f, 128.0f - 0.00390625f);

    const float LN2F = 0.6931471805599453f;
    return __fsub_rn(__fmul_rn(shiftf, LN2F), acc);
}

__device__ __forceinline__ v4f raven4(v4f v) {
    v4f r;
    r.x = raven_elem(v.x);
    r.y = raven_elem(v.y);
    r.z = raven_elem(v.z);
    r.w = raven_elem(v.w);
    return r;
}

__global__ void __launch_bounds__(256)
raven_kernel(const v4f* __restrict__ x, v4f* __restrict__ out, int q4) {
    // four coalesced streams: [0,q4), [q4,2q4), [2q4,3q4), [3q4,4q4)
    int stride = gridDim.x * blockDim.x;
    for (int i = blockIdx.x * blockDim.x + threadIdx.x; i < q4; i += stride) {
        v4f a = __builtin_nontemporal_load(x + i);
        v4f b = __builtin_nontemporal_load(x + i + q4);
        v4f c = __builtin_nontemporal_load(x + i + 2 * q4);
        v4f d = __builtin_nontemporal_load(x + i + 3 * q4);
        v4f ra = raven4(a);
        v4f rb = raven4(b);
        v4f rc = raven4(c);
        v4f rd = raven4(d);
        __builtin_nontemporal_store(ra, out + i);
        __builtin_nontemporal_store(rb, out + i + q4);
        __builtin_nontemporal_store(rc, out + i + 2 * q4);
        __builtin_nontemporal_store(rd, out + i + 3 * q4);
    }
}

extern "C" void kernel_launch(void* const* d_in, const int* in_sizes, int n_in,
                              void* d_out, int out_size, void* d_ws, size_t ws_size,
                              hipStream_t stream) {
    const float* x = (const float*)d_in[0];
    float* out = (float*)d_out;
    int n = in_sizes[0];          // 67,108,864 (divisible by 16)
    int q4 = n >> 4;              // float4 count per quarter-stream
    const int block = 256;
    const int grid = 2048;        // 8 blocks/CU, 32 waves/CU; 8 iters/thread
    raven_kernel<<<grid, block, 0, stream>>>(
        reinterpret_cast<const v4f*>(x), reinterpret_cast<v4f*>(out), q4);
}

// Round 5
// 100.342 us; speedup vs baseline: 1.0354x; 1.0354x over previous
//
#include <hip/hip_runtime.h>

// RAVENlog: out = shift*ln2 - Horner4_quantized(0.75 - x*2^-shift)
// shift = floor(log2(x)) + 1 (exact via exponent bits; x in [0.25, 8) is normal)
//
// R5: R3 structure (2 nontemporal streams; R4's 4 streams regressed) plus two
// domain-safe VALU cuts, bit-identical on x in [0.25,8):
//  - quantize clamps to [-128, 128-2^-fw] never fire (acc stays in [-0.12,1.61],
//    var in (-0.25,0.25]) -> dropped.
//  - first Horner step is q(0*var+c3) = rint(c3*32)/32 = 0.78125 exactly -> const.
// Remaining steps keep __f*_rn (no FMA contraction) + rintf (round-half-even)
// so arithmetic matches the jnp reference's rounding bit-exactly.

typedef float v4f __attribute__((ext_vector_type(4)));

__device__ __forceinline__ float qstep(float acc, float var, float c,
                                       float s, float invs) {
    float t = __fadd_rn(__fmul_rn(acc, var), c);   // no FMA: match jnp rounding
    return __fmul_rn(rintf(__fmul_rn(t, s)), invs); // exact pow2 scale, rne
}

__device__ __forceinline__ float raven_elem(float x) {
    unsigned int b = __float_as_uint(x);
    float shiftf = (float)((int)((b >> 23) & 0xFFu) - 126);
    float m = __uint_as_float((b & 0x007FFFFFu) | 0x3F000000u);
    float var = __fsub_rn(0.75f, m);   // exact

    const float c0 = 0.2876820724517809f;
    const float c1 = 1.3333333333333333f;
    const float c2 = 0.8888888888888888f;

    float acc = 0.78125f;              // = quantize(c3, fw=5), computed exactly
    acc = qstep(acc, var, c2,  64.0f, 0.015625f);    // fw=6
    acc = qstep(acc, var, c1, 128.0f, 0.0078125f);   // fw=7
    acc = qstep(acc, var, c0, 256.0f, 0.00390625f);  // fw=8

    const float LN2F = 0.6931471805599453f;
    return __fsub_rn(__fmul_rn(shiftf, LN2F), acc);
}

__device__ __forceinline__ v4f raven4(v4f v) {
    v4f r;
    r.x = raven_elem(v.x);
    r.y = raven_elem(v.y);
    r.z = raven_elem(v.z);
    r.w = raven_elem(v.w);
    return r;
}

__global__ void __launch_bounds__(256)
raven_kernel(const v4f* __restrict__ x, v4f* __restrict__ out, int half4) {
    // two coalesced streams: [0, half4) and [half4, 2*half4)
    int stride = gridDim.x * blockDim.x;
    for (int i = blockIdx.x * blockDim.x + threadIdx.x; i < half4; i += stride) {
        v4f a = __builtin_nontemporal_load(x + i);
        v4f b = __builtin_nontemporal_load(x + i + half4);
        v4f ra = raven4(a);
        v4f rb = raven4(b);
        __builtin_nontemporal_store(ra, out + i);
        __builtin_nontemporal_store(rb, out + i + half4);
    }
}

extern "C" void kernel_launch(void* const* d_in, const int* in_sizes, int n_in,
                              void* d_out, int out_size, void* d_ws, size_t ws_size,
                              hipStream_t stream) {
    const float* x = (const float*)d_in[0];
    float* out = (float*)d_out;
    int n = in_sizes[0];          // 67,108,864 (divisible by 8)
    int half4 = n >> 3;           // float4 count per half-stream
    const int block = 256;
    const int grid = 2048;        // 8 blocks/CU, 32 waves/CU
    raven_kernel<<<grid, block, 0, stream>>>(
        reinterpret_cast<const v4f*>(x), reinterpret_cast<v4f*>(out), half4);
}

// Round 7
// 85.093 us; speedup vs baseline: 1.2210x; 1.1792x over previous
//
#include <hip/hip_runtime.h>

// RAVENlog: out = shift*ln2 - Horner4_quantized(0.75 - x*2^-shift)
// shift = floor(log2(x)) + 1 (exact via exponent bits; x in [0.25, 8) is normal)
//
// R7: R6 failed POST-TIMING revalidation (absmax 90.08 = signature of an input
// element read as 0.0 during a timed replay: out(x=0) = -126*ln2 - poly(0.25)
// = -88.02 vs ref ~2.06). Kernel is deterministic and never writes d_in ->
// suspect the `nt` LOAD hint (rare stale/zero read across many graph replays).
// Fix: plain cached loads; keep NT stores (d_out fully rewritten each call,
// readback-after-sync validated clean in every session). Keep single-stream
// (R6 timing: 97.0us vs 100.3 two-stream).
// Math: clamps dropped + first Horner step folded (bit-identical on x in
// [0.25,8)); __f*_rn blocks FMA contraction; rintf = round-half-even = jnp.

typedef float v4f __attribute__((ext_vector_type(4)));

__device__ __forceinline__ float qstep(float acc, float var, float c,
                                       float s, float invs) {
    float t = __fadd_rn(__fmul_rn(acc, var), c);   // no FMA: match jnp rounding
    return __fmul_rn(rintf(__fmul_rn(t, s)), invs); // exact pow2 scale, rne
}

__device__ __forceinline__ float raven_elem(float x) {
    unsigned int b = __float_as_uint(x);
    float shiftf = (float)((int)((b >> 23) & 0xFFu) - 126);
    float m = __uint_as_float((b & 0x007FFFFFu) | 0x3F000000u);
    float var = __fsub_rn(0.75f, m);   // exact

    const float c0 = 0.2876820724517809f;
    const float c1 = 1.3333333333333333f;
    const float c2 = 0.8888888888888888f;

    float acc = 0.78125f;              // = quantize(c3, fw=5), exact
    acc = qstep(acc, var, c2,  64.0f, 0.015625f);    // fw=6
    acc = qstep(acc, var, c1, 128.0f, 0.0078125f);   // fw=7
    acc = qstep(acc, var, c0, 256.0f, 0.00390625f);  // fw=8

    const float LN2F = 0.6931471805599453f;
    return __fsub_rn(__fmul_rn(shiftf, LN2F), acc);
}

__device__ __forceinline__ v4f raven4(v4f v) {
    v4f r;
    r.x = raven_elem(v.x);
    r.y = raven_elem(v.y);
    r.z = raven_elem(v.z);
    r.w = raven_elem(v.w);
    return r;
}

__global__ void __launch_bounds__(256)
raven_kernel(const v4f* __restrict__ x, v4f* __restrict__ out, int n4) {
    int stride = gridDim.x * blockDim.x;
    for (int i = blockIdx.x * blockDim.x + threadIdx.x; i < n4; i += stride) {
        v4f a = x[i];                       // plain cached load (no nt hint)
        v4f ra = raven4(a);
        __builtin_nontemporal_store(ra, out + i);
    }
}

extern "C" void kernel_launch(void* const* d_in, const int* in_sizes, int n_in,
                              void* d_out, int out_size, void* d_ws, size_t ws_size,
                              hipStream_t stream) {
    const float* x = (const float*)d_in[0];
    float* out = (float*)d_out;
    int n = in_sizes[0];          // 67,108,864 (divisible by 4)
    int n4 = n >> 2;              // 16.8M float4; 32 iters/thread
    const int block = 256;
    const int grid = 2048;        // 8 blocks/CU, 32 waves/CU
    raven_kernel<<<grid, block, 0, stream>>>(
        reinterpret_cast<const v4f*>(x), reinterpret_cast<v4f*>(out), n4);
}